// Round 7
// baseline (215.408 us; speedup 1.0000x reference)
//
#include <hip/hip_runtime.h>

#define NN 100000
#define NE 1200000
#define DD 64
#define NBUCK 196        // ceil(NN/512) coarse buckets (dst >> 9)
#define BCAP 7168        // bucket capacity: mean 6144, sigma ~78 -> +13 sigma
#define TILE 4096        // edges per pass-1 block
#define NB1 293          // ceil(NE/TILE)
#define NB_G 1563        // ceil(NN/64) gemm blocks
#define NZS 391          // slots-zeroing blocks: ceil(NN*16 uint4 / 4096)
#define FIX25 33554432.0f
#define FIX25_INV (1.0f/33554432.0f)

typedef short bf16x8 __attribute__((ext_vector_type(8)));
typedef float f32x4  __attribute__((ext_vector_type(4)));

static __device__ __forceinline__ unsigned short f2bf(float f) {
    unsigned int u = __float_as_uint(f);
    unsigned int r = (u + 0x7fffu + ((u >> 16) & 1u)) >> 16;   // RNE
    return (unsigned short)r;
}
static __device__ __forceinline__ float bf2f(unsigned short s) {
    return __uint_as_float(((unsigned int)s) << 16);
}

// ============= shared GEMM body: h16 = bf16(x @ W) =============
// Stages W^T (bf16) straight from the fp32 W: 16 KB, L2-broadcast across all
// blocks, coalesced in 64 B groups -> no prep kernel / Wt buffer needed.

static __device__ __forceinline__ void gemm_body(
    const float* __restrict__ x, const float* __restrict__ W,
    unsigned short* __restrict__ h16, int r0, int t,
    unsigned short* Xs, unsigned short* Ws)
{
    {   // stage W^T -> Ws[col][k] bf16: 16 elems/thread
        int col = t >> 2, seg = (t & 3) * 16;
        unsigned short tmp[16];
        #pragma unroll
        for (int i = 0; i < 16; ++i)
            tmp[i] = f2bf(W[(size_t)(seg + i) * 64 + col]);
        *(uint4*)&Ws[col * 72 + seg]     = *(uint4*)&tmp[0];
        *(uint4*)&Ws[col * 72 + seg + 8] = *(uint4*)&tmp[8];
    }
    {   // stage X: fp32 -> bf16, 16 floats/thread
        int row = t >> 2, seg = (t & 3) * 16;
        int gr = r0 + row;
        float4 v0 = {0,0,0,0}, v1 = v0, v2 = v0, v3 = v0;
        if (gr < NN) {
            const float4* p = (const float4*)(x + (size_t)gr * DD + seg);
            v0 = p[0]; v1 = p[1]; v2 = p[2]; v3 = p[3];
        }
        ushort4 h0 = { f2bf(v0.x), f2bf(v0.y), f2bf(v0.z), f2bf(v0.w) };
        ushort4 h1 = { f2bf(v1.x), f2bf(v1.y), f2bf(v1.z), f2bf(v1.w) };
        ushort4 h2 = { f2bf(v2.x), f2bf(v2.y), f2bf(v2.z), f2bf(v2.w) };
        ushort4 h3 = { f2bf(v3.x), f2bf(v3.y), f2bf(v3.z), f2bf(v3.w) };
        *(ushort4*)&Xs[row * 72 + seg]      = h0;
        *(ushort4*)&Xs[row * 72 + seg + 4]  = h1;
        *(ushort4*)&Xs[row * 72 + seg + 8]  = h2;
        *(ushort4*)&Xs[row * 72 + seg + 12] = h3;
    }
    __syncthreads();

    const int wv = t >> 6;
    const int ln = t & 63;
    const int m  = ln & 15;
    const int q  = ln >> 4;
    const int arow = wv * 16 + m;

    bf16x8 a0 = *(const bf16x8*)&Xs[arow * 72 + q * 8];
    bf16x8 a1 = *(const bf16x8*)&Xs[arow * 72 + 32 + q * 8];

    f32x4 acc[4];
    #pragma unroll
    for (int c = 0; c < 4; ++c) {
        bf16x8 b0 = *(const bf16x8*)&Ws[(c * 16 + m) * 72 + q * 8];
        bf16x8 b1 = *(const bf16x8*)&Ws[(c * 16 + m) * 72 + 32 + q * 8];
        f32x4 z = {0.f, 0.f, 0.f, 0.f};
        z = __builtin_amdgcn_mfma_f32_16x16x32_bf16(a0, b0, z, 0, 0, 0);
        z = __builtin_amdgcn_mfma_f32_16x16x32_bf16(a1, b1, z, 0, 0, 0);
        acc[c] = z;
    }

    #pragma unroll
    for (int r = 0; r < 4; ++r) {
        int grow = r0 + wv * 16 + q * 4 + r;
        if (grow < NN) {
            #pragma unroll
            for (int c = 0; c < 4; ++c)
                h16[(size_t)grow * DD + c * 16 + m] = f2bf(acc[c][r]);
        }
    }
}

// ============= pass 1: binning + gemm1 + slots-zeroing, one grid =============
// Blocks [0,NB1): bin TILE edges into NBUCK buckets (2-sweep, LDS counts).
// Blocks [NB1, NB1+NB_G): layer-1 GEMM.
// Blocks [NB1+NB_G, +NZS): zero the slots buffer (25.6 MB coalesced) so every
// speculative gather read past deg decodes to e=0 -> hot row 0, norm masked.
// All complete before pass2/gather dispatches (stream order).

__global__ __launch_bounds__(256) void pass1_gemm(
    const int* __restrict__ src, const int* __restrict__ dst,
    const float* __restrict__ ew, int* __restrict__ cursor,
    unsigned long long* __restrict__ stage, unsigned int* __restrict__ slots,
    const float* __restrict__ x, const float* __restrict__ W1,
    unsigned short* __restrict__ h16)
{
    __shared__ unsigned short Xs[64 * 72];
    __shared__ unsigned short Ws[64 * 72];
    __shared__ int cnt[NBUCK];
    __shared__ int resv[NBUCK];

    const int t = threadIdx.x;

    if (blockIdx.x >= NB1 + NB_G) {      // slots zeroing
        const int zb = blockIdx.x - (NB1 + NB_G);
        uint4* sl = (uint4*)slots;
        const size_t total = (size_t)NN * 16;       // uint4 count
        size_t base = (size_t)zb * 4096 + t;
        const uint4 z = {0u, 0u, 0u, 0u};
        #pragma unroll
        for (int i = 0; i < 16; ++i) {
            size_t idx = base + (size_t)i * 256;
            if (idx < total) sl[idx] = z;
        }
        return;
    }

    if (blockIdx.x >= NB1) {
        gemm_body(x, W1, h16, (blockIdx.x - NB1) * 64, t, Xs, Ws);
        return;
    }

    const int base = blockIdx.x * TILE;
    if (t < NBUCK) cnt[t] = 0;
    __syncthreads();

    #pragma unroll
    for (int k = 0; k < TILE / 256; ++k) {
        int e = base + k * 256 + t;
        if (e < NE) atomicAdd(&cnt[dst[e] >> 9], 1);
    }
    __syncthreads();
    if (t < NBUCK) {
        int c = cnt[t];
        resv[t] = c ? atomicAdd(&cursor[t], c) : 0;
        cnt[t] = 0;
    }
    __syncthreads();
    #pragma unroll
    for (int k = 0; k < TILE / 256; ++k) {
        int e = base + k * 256 + t;
        if (e < NE) {
            int d = dst[e];
            int b = d >> 9;
            int r = atomicAdd(&cnt[b], 1);
            int pos = resv[b] + r;
            if (pos < BCAP) {
                unsigned int meta = ((unsigned int)(d & 511) << 17) |
                                    (unsigned int)src[e];
                stage[(size_t)b * BCAP + pos] =
                    ((unsigned long long)meta << 32) | __float_as_uint(ew[e]);
            }
        }
    }
}

// ============= pass 2: per-bucket rank -> fixed-stride slots + degdis ========
// One block (512 thr) per bucket, single sweep: LDS atomic rank r + fixpoint
// wsum; slot address is direct: slots[(n0+dl)*64 + r]. Tails stay zero
// (bulk-zeroed in pass1's grid). degdis[node] = (dis bits & ~63) | deg.

__global__ __launch_bounds__(512) void pass2(
    const unsigned long long* __restrict__ stage, const int* __restrict__ cursor,
    unsigned int* __restrict__ slots, unsigned int* __restrict__ degdis)
{
    __shared__ int cnt[512];
    __shared__ unsigned sum[512];

    const int b = blockIdx.x;
    const int t = threadIdx.x;
    const int n0 = b << 9;
    const int cntb = min(cursor[b], BCAP);

    cnt[t] = 0; sum[t] = 0;
    __syncthreads();

    for (int k = t; k < cntb; k += 512) {
        unsigned long long E = stage[(size_t)b * BCAP + k];
        unsigned int meta = (unsigned int)(E >> 32);
        int dl = meta >> 17;
        float w = __uint_as_float((unsigned int)E);
        int r = atomicAdd(&cnt[dl], 1);
        atomicAdd(&sum[dl], (unsigned)(w * FIX25));
        if (r < 63)
            slots[(size_t)(n0 + dl) * 64 + r] =
                ((meta & 0x1ffffu) << 15) | (f2bf(w) & 0x7fffu);
    }
    __syncthreads();

    int node = n0 + t;
    if (node < NN) {
        float deg = 1.0f + (float)sum[t] * FIX25_INV;
        float di = rsqrtf(deg);
        degdis[node] = (__float_as_uint(di) & ~63u) |
                       (unsigned)min(cnt[t], 63);
    }
}

// ============= gather (one wave per node, 32-edge speculative issue) ========
// Lane = (g,l): g = lane>>4 edge slot in quad, l = lane&15 -> channels 4l..+3.
// Slot words are wave-uniform -> scalar loads; the first 32 edge words issue
// with NO prior load (2-level chain: word -> {h16 row, degdis[src]} parallel).
// Slots past deg are guaranteed ZERO -> speculative lanes hit hot row 0 and
// the norm is masked 0 by deg. 99.95% of nodes (lambda~12) need one epoch.

template <bool FINAL>
__global__ __launch_bounds__(256) void gather(
    const unsigned short* __restrict__ h16, const float* __restrict__ bias,
    const unsigned int* __restrict__ degdis, const unsigned int* __restrict__ slots,
    const float* __restrict__ prev, float* __restrict__ out)
{
    const int node = __builtin_amdgcn_readfirstlane(
        (blockIdx.x * blockDim.x + threadIdx.x) >> 6);
    const int lane = threadIdx.x & 63;
    if (node >= NN) return;

    const int g = lane >> 4;
    const int l = lane & 15;
    const int l4 = l << 2;

    const unsigned int* seg = slots + (size_t)node * 64;

    const unsigned int dd = degdis[node];
    const int deg = dd & 63;
    const float di = __uint_as_float(dd & ~63u);

    // parallel with edge chain; consumed only in the epilogue
    const ushort4 hs = *(const ushort4*)(h16 + (size_t)node * DD + l4);
    const float4  bb = *(const float4*)(bias + l4);
    float4 p = {0.f, 0.f, 0.f, 0.f};
    if (FINAL) p = *(const float4*)(prev + (size_t)node * DD + l4);

    f32x4 acc0 = {0,0,0,0}, acc1 = {0,0,0,0}, acc2 = {0,0,0,0}, acc3 = {0,0,0,0};

#define QUADX(q, joff, rq, nq)                                                 \
    {                                                                          \
        unsigned w0 = seg[(joff) + 4*q + 0], w1 = seg[(joff) + 4*q + 1];       \
        unsigned w2 = seg[(joff) + 4*q + 2], w3 = seg[(joff) + 4*q + 3];       \
        unsigned ea = (g & 1) ? w1 : w0;                                       \
        unsigned eb = (g & 1) ? w3 : w2;                                       \
        unsigned e  = (g & 2) ? eb : ea;                                       \
        unsigned srow = e >> 15;                                               \
        srow = (srow < NN) ? srow : 0u;                                        \
        float dsrc = __uint_as_float(degdis[srow] & ~63u);                     \
        rq = *(const ushort4*)(h16 + ((size_t)srow << 6) + l4);                \
        float nv_ = bf2f((unsigned short)(e & 0x7fffu)) * di * dsrc;           \
        nq = ((joff) + 4*q + g < deg) ? nv_ : 0.f;                             \
    }
#define FMA4(rq, nq, ac)                                                       \
    ac[0] = fmaf(nq, bf2f(rq.x), ac[0]);                                       \
    ac[1] = fmaf(nq, bf2f(rq.y), ac[1]);                                       \
    ac[2] = fmaf(nq, bf2f(rq.z), ac[2]);                                       \
    ac[3] = fmaf(nq, bf2f(rq.w), ac[3]);

    {   // first 32 edges: unconditional, zero-dependency issue
        ushort4 r0, r1, r2, r3, r4, r5, r6, r7;
        float n0, n1, n2, n3, n4, n5, n6, n7;
        QUADX(0, 0, r0, n0)
        QUADX(1, 0, r1, n1)
        QUADX(2, 0, r2, n2)
        QUADX(3, 0, r3, n3)
        QUADX(4, 0, r4, n4)
        QUADX(5, 0, r5, n5)
        QUADX(6, 0, r6, n6)
        QUADX(7, 0, r7, n7)
        FMA4(r0, n0, acc0)
        FMA4(r1, n1, acc1)
        FMA4(r2, n2, acc2)
        FMA4(r3, n3, acc3)
        FMA4(r4, n4, acc0)
        FMA4(r5, n5, acc1)
        FMA4(r6, n6, acc2)
        FMA4(r7, n7, acc3)
    }
    if (deg > 32) {
        for (int j = 32; j < deg; j += 16) {
            ushort4 r0, r1, r2, r3;
            float n0, n1, n2, n3;
            QUADX(0, j, r0, n0)
            QUADX(1, j, r1, n1)
            QUADX(2, j, r2, n2)
            QUADX(3, j, r3, n3)
            FMA4(r0, n0, acc0)
            FMA4(r1, n1, acc1)
            FMA4(r2, n2, acc2)
            FMA4(r3, n3, acc3)
        }
    }
#undef QUADX
#undef FMA4

    float s0 = (acc0[0] + acc1[0]) + (acc2[0] + acc3[0]);
    float s1 = (acc0[1] + acc1[1]) + (acc2[1] + acc3[1]);
    float s2 = (acc0[2] + acc1[2]) + (acc2[2] + acc3[2]);
    float s3 = (acc0[3] + acc1[3]) + (acc2[3] + acc3[3]);

    s0 += __shfl_xor(s0, 16); s1 += __shfl_xor(s1, 16);
    s2 += __shfl_xor(s2, 16); s3 += __shfl_xor(s3, 16);
    s0 += __shfl_xor(s0, 32); s1 += __shfl_xor(s1, 32);
    s2 += __shfl_xor(s2, 32); s3 += __shfl_xor(s3, 32);

    if (g == 0) {
        const float dsq = di * di;
        float v0 = fmaxf(fmaf(dsq, bf2f(hs.x), bb.x) + s0, 0.f);
        float v1 = fmaxf(fmaf(dsq, bf2f(hs.y), bb.y) + s1, 0.f);
        float v2 = fmaxf(fmaf(dsq, bf2f(hs.z), bb.z) + s2, 0.f);
        float v3 = fmaxf(fmaf(dsq, bf2f(hs.w), bb.w) + s3, 0.f);
        float4 o;
        if (FINAL) {
            o.x = 0.5f * (p.x + v0); o.y = 0.5f * (p.y + v1);
            o.z = 0.5f * (p.z + v2); o.w = 0.5f * (p.w + v3);
        } else {
            o.x = v0; o.y = v1; o.z = v2; o.w = v3;
        }
        *(float4*)(out + (size_t)node * DD + l4) = o;
    }
}

__global__ __launch_bounds__(256) void gemm_mfma(
    const float* __restrict__ x, const float* __restrict__ W,
    unsigned short* __restrict__ h16)
{
    __shared__ unsigned short Xs[64 * 72];
    __shared__ unsigned short Ws[64 * 72];
    gemm_body(x, W, h16, blockIdx.x * 64, threadIdx.x, Xs, Ws);
}

// ============= launch =============

extern "C" void kernel_launch(void* const* d_in, const int* in_sizes, int n_in,
                              void* d_out, int out_size, void* d_ws, size_t ws_size,
                              hipStream_t stream) {
    const float* x   = (const float*)d_in[0];
    const int*   ei  = (const int*)d_in[1];
    const float* ewt = (const float*)d_in[2];
    const float* W1  = (const float*)d_in[3];
    const float* b1  = (const float*)d_in[4];
    const float* W2  = (const float*)d_in[5];
    const float* b2  = (const float*)d_in[6];
    float* out = (float*)d_out;

    const int* srcv = ei;
    const int* dstv = ei + NE;

    // workspace layout, 4B slots (d_ws 16B aligned); ~50 MB total
    float* wsf = (float*)d_ws;
    int* cursor = (int*)wsf;                                        // [0,256)
    unsigned int* degdis = (unsigned int*)(wsf + 4352);             // 100000 -> pad 104448
    unsigned long long* stage = (unsigned long long*)(wsf + 104448);// NBUCK*BCAP u64
    unsigned int* slots = (unsigned int*)(wsf + 104448 + 2 * NBUCK * BCAP);
    unsigned short* h16 = (unsigned short*)(slots + (size_t)NN * 64); // NN*64 bf16

    const int GB = (NN * 64) / 256;          // 25000 blocks, one wave per node

    hipMemsetAsync(cursor, 0, NBUCK * sizeof(int), stream);
    pass1_gemm<<<NB1 + NB_G + NZS, 256, 0, stream>>>(srcv, dstv, ewt, cursor,
                                                     stage, slots, x, W1, h16);
    pass2<<<NBUCK, 512, 0, stream>>>(stage, cursor, slots, degdis);

    gather<false><<<GB, 256, 0, stream>>>(h16, b1, degdis, slots, nullptr, out);
    gemm_mfma<<<NB_G, 256, 0, stream>>>(out, W2, h16);
    gather<true><<<GB, 256, 0, stream>>>(h16, b2, degdis, slots, out, out);
}

// Round 8
// 202.272 us; speedup vs baseline: 1.0649x; 1.0649x over previous
//
#include <hip/hip_runtime.h>

#define NN 100000
#define NE 1200000
#define DD 64
#define NBUCK 196        // ceil(NN/512) coarse buckets (dst >> 9)
#define BCAP 7168        // bucket capacity: mean 6144, sigma ~78 -> +13 sigma
#define TILE 4096        // edges per pass-1 block
#define NB1 293          // ceil(NE/TILE)
#define NB_G 1563        // ceil(NN/64) gemm blocks
#define FIX25 33554432.0f
#define FIX25_INV (1.0f/33554432.0f)

typedef short bf16x8 __attribute__((ext_vector_type(8)));
typedef float f32x4  __attribute__((ext_vector_type(4)));

static __device__ __forceinline__ unsigned short f2bf(float f) {
    unsigned int u = __float_as_uint(f);
    unsigned int r = (u + 0x7fffu + ((u >> 16) & 1u)) >> 16;   // RNE
    return (unsigned short)r;
}
static __device__ __forceinline__ float bf2f(unsigned short s) {
    return __uint_as_float(((unsigned int)s) << 16);
}

// ============= shared GEMM body: h16 = bf16(x @ W) =============
// Stages W^T (bf16) straight from the fp32 W: 16 KB, L2-broadcast across all
// blocks -> no prep kernel / Wt buffer needed.

static __device__ __forceinline__ void gemm_body(
    const float* __restrict__ x, const float* __restrict__ W,
    unsigned short* __restrict__ h16, int r0, int t,
    unsigned short* Xs, unsigned short* Ws)
{
    {   // stage W^T -> Ws[col][k] bf16: 16 elems/thread
        int col = t >> 2, seg = (t & 3) * 16;
        unsigned short tmp[16];
        #pragma unroll
        for (int i = 0; i < 16; ++i)
            tmp[i] = f2bf(W[(size_t)(seg + i) * 64 + col]);
        *(uint4*)&Ws[col * 72 + seg]     = *(uint4*)&tmp[0];
        *(uint4*)&Ws[col * 72 + seg + 8] = *(uint4*)&tmp[8];
    }
    {   // stage X: fp32 -> bf16, 16 floats/thread
        int row = t >> 2, seg = (t & 3) * 16;
        int gr = r0 + row;
        float4 v0 = {0,0,0,0}, v1 = v0, v2 = v0, v3 = v0;
        if (gr < NN) {
            const float4* p = (const float4*)(x + (size_t)gr * DD + seg);
            v0 = p[0]; v1 = p[1]; v2 = p[2]; v3 = p[3];
        }
        ushort4 h0 = { f2bf(v0.x), f2bf(v0.y), f2bf(v0.z), f2bf(v0.w) };
        ushort4 h1 = { f2bf(v1.x), f2bf(v1.y), f2bf(v1.z), f2bf(v1.w) };
        ushort4 h2 = { f2bf(v2.x), f2bf(v2.y), f2bf(v2.z), f2bf(v2.w) };
        ushort4 h3 = { f2bf(v3.x), f2bf(v3.y), f2bf(v3.z), f2bf(v3.w) };
        *(ushort4*)&Xs[row * 72 + seg]      = h0;
        *(ushort4*)&Xs[row * 72 + seg + 4]  = h1;
        *(ushort4*)&Xs[row * 72 + seg + 8]  = h2;
        *(ushort4*)&Xs[row * 72 + seg + 12] = h3;
    }
    __syncthreads();

    const int wv = t >> 6;
    const int ln = t & 63;
    const int m  = ln & 15;
    const int q  = ln >> 4;
    const int arow = wv * 16 + m;

    bf16x8 a0 = *(const bf16x8*)&Xs[arow * 72 + q * 8];
    bf16x8 a1 = *(const bf16x8*)&Xs[arow * 72 + 32 + q * 8];

    f32x4 acc[4];
    #pragma unroll
    for (int c = 0; c < 4; ++c) {
        bf16x8 b0 = *(const bf16x8*)&Ws[(c * 16 + m) * 72 + q * 8];
        bf16x8 b1 = *(const bf16x8*)&Ws[(c * 16 + m) * 72 + 32 + q * 8];
        f32x4 z = {0.f, 0.f, 0.f, 0.f};
        z = __builtin_amdgcn_mfma_f32_16x16x32_bf16(a0, b0, z, 0, 0, 0);
        z = __builtin_amdgcn_mfma_f32_16x16x32_bf16(a1, b1, z, 0, 0, 0);
        acc[c] = z;
    }

    #pragma unroll
    for (int r = 0; r < 4; ++r) {
        int grow = r0 + wv * 16 + q * 4 + r;
        if (grow < NN) {
            #pragma unroll
            for (int c = 0; c < 4; ++c)
                h16[(size_t)grow * DD + c * 16 + m] = f2bf(acc[c][r]);
        }
    }
}

// ============= pass 1: coarse binning (2-sweep, LDS counts) + gemm1 fused =====
// Blocks [0,NB1): bin TILE edges into NBUCK buckets; stage entry u64:
//   [dl:9 | src:17]:32 high, fp32 ew low. One cursor atomic per (block,bucket).
// Blocks [NB1, NB1+NB_G): layer-1 GEMM (independent -> co-scheduled).

__global__ __launch_bounds__(256) void pass1_gemm(
    const int* __restrict__ src, const int* __restrict__ dst,
    const float* __restrict__ ew, int* __restrict__ cursor,
    unsigned long long* __restrict__ stage,
    const float* __restrict__ x, const float* __restrict__ W1,
    unsigned short* __restrict__ h16)
{
    __shared__ unsigned short Xs[64 * 72];
    __shared__ unsigned short Ws[64 * 72];
    __shared__ int cnt[NBUCK];
    __shared__ int resv[NBUCK];

    const int t = threadIdx.x;

    if (blockIdx.x >= NB1) {
        gemm_body(x, W1, h16, (blockIdx.x - NB1) * 64, t, Xs, Ws);
        return;
    }

    const int base = blockIdx.x * TILE;
    if (t < NBUCK) cnt[t] = 0;
    __syncthreads();

    #pragma unroll
    for (int k = 0; k < TILE / 256; ++k) {
        int e = base + k * 256 + t;
        if (e < NE) atomicAdd(&cnt[dst[e] >> 9], 1);
    }
    __syncthreads();
    if (t < NBUCK) {
        int c = cnt[t];
        resv[t] = c ? atomicAdd(&cursor[t], c) : 0;
        cnt[t] = 0;
    }
    __syncthreads();
    #pragma unroll
    for (int k = 0; k < TILE / 256; ++k) {
        int e = base + k * 256 + t;
        if (e < NE) {
            int d = dst[e];
            int b = d >> 9;
            int r = atomicAdd(&cnt[b], 1);
            int pos = resv[b] + r;
            if (pos < BCAP) {
                unsigned int meta = ((unsigned int)(d & 511) << 17) |
                                    (unsigned int)src[e];
                stage[(size_t)b * BCAP + pos] =
                    ((unsigned long long)meta << 32) | __float_as_uint(ew[e]);
            }
        }
    }
}

// ============= pass 2: per-bucket rank -> fixed-stride slots + degdis ========
// One block (512 thr) per bucket, single sweep: LDS atomic rank r + fixpoint
// wsum; slot address is direct: slots[(n0+dl)*64 + r]. No staging, no scan.
// degdis[node] = (rsqrt(1+wsum) bits & ~63) | deg   (6 stolen mantissa bits
// cost ~2^-17 relative -- far below the bf16 norm quantization).
// NOTE: no tail handling -- stale words past deg decode to srow >= NN (the
// harness poison) and gather clamps them to hot row 0 with norm masked 0.
// Measured: explicit tail-zeroing is a net regression (r6), bulk-zeroing too (r7).

__global__ __launch_bounds__(512) void pass2(
    const unsigned long long* __restrict__ stage, const int* __restrict__ cursor,
    unsigned int* __restrict__ slots, unsigned int* __restrict__ degdis)
{
    __shared__ int cnt[512];
    __shared__ unsigned sum[512];

    const int b = blockIdx.x;
    const int t = threadIdx.x;
    const int n0 = b << 9;
    const int cntb = min(cursor[b], BCAP);

    cnt[t] = 0; sum[t] = 0;
    __syncthreads();

    for (int k = t; k < cntb; k += 512) {
        unsigned long long E = stage[(size_t)b * BCAP + k];
        unsigned int meta = (unsigned int)(E >> 32);
        int dl = meta >> 17;
        float w = __uint_as_float((unsigned int)E);
        int r = atomicAdd(&cnt[dl], 1);
        atomicAdd(&sum[dl], (unsigned)(w * FIX25));
        if (r < 63)
            slots[(size_t)(n0 + dl) * 64 + r] =
                ((meta & 0x1ffffu) << 15) | (f2bf(w) & 0x7fffu);
    }
    __syncthreads();

    int node = n0 + t;
    if (node < NN) {
        float deg = 1.0f + (float)sum[t] * FIX25_INV;
        float di = rsqrtf(deg);
        degdis[node] = (__float_as_uint(di) & ~63u) |
                       (unsigned)min(cnt[t], 63);
    }
}

// ============= gather (one wave per node, 16-edge speculative issue) ========
// Lane = (g,l): g = lane>>4 edge slot in quad, l = lane&15 -> channels 4l..+3.
// Edge-word addresses depend only on `node`, so the first 16 words issue with
// NO prior load (2-level chain: word -> {h16 row, degdis[src]} in parallel).
// Norm computed in-flight from degdis (400 KB, L2-resident) -- no bake pass.
// 16-edge speculation is the measured knee: 32-wide went VALU-bound (r7,
// VALUBusy 94%, +15 us/gather). Stale tail words clamp to row 0, norm 0.

template <bool FINAL>
__global__ __launch_bounds__(256) void gather(
    const unsigned short* __restrict__ h16, const float* __restrict__ bias,
    const unsigned int* __restrict__ degdis, const unsigned int* __restrict__ slots,
    const float* __restrict__ prev, float* __restrict__ out)
{
    const int node = __builtin_amdgcn_readfirstlane(
        (blockIdx.x * blockDim.x + threadIdx.x) >> 6);
    const int lane = threadIdx.x & 63;
    if (node >= NN) return;

    const int g = lane >> 4;
    const int l = lane & 15;
    const int l4 = l << 2;

    const unsigned int* seg = slots + (size_t)node * 64;

    const unsigned int dd = degdis[node];
    const int deg = dd & 63;
    const float di = __uint_as_float(dd & ~63u);

    // parallel with edge chain; consumed only in the epilogue
    const ushort4 hs = *(const ushort4*)(h16 + (size_t)node * DD + l4);
    const float4  bb = *(const float4*)(bias + l4);
    float4 p = {0.f, 0.f, 0.f, 0.f};
    if (FINAL) p = *(const float4*)(prev + (size_t)node * DD + l4);

    f32x4 acc0 = {0,0,0,0}, acc1 = {0,0,0,0}, acc2 = {0,0,0,0}, acc3 = {0,0,0,0};

#define QUADX(q, joff, rq, nq)                                                 \
    {                                                                          \
        unsigned w0 = seg[(joff) + 4*q + 0], w1 = seg[(joff) + 4*q + 1];       \
        unsigned w2 = seg[(joff) + 4*q + 2], w3 = seg[(joff) + 4*q + 3];       \
        unsigned ea = (g & 1) ? w1 : w0;                                       \
        unsigned eb = (g & 1) ? w3 : w2;                                       \
        unsigned e  = (g & 2) ? eb : ea;                                       \
        unsigned srow = e >> 15;                                               \
        srow = (srow < NN) ? srow : 0u;                                        \
        float dsrc = __uint_as_float(degdis[srow] & ~63u);                     \
        rq = *(const ushort4*)(h16 + ((size_t)srow << 6) + l4);                \
        float nv_ = bf2f((unsigned short)(e & 0x7fffu)) * di * dsrc;           \
        nq = ((joff) + 4*q + g < deg) ? nv_ : 0.f;                             \
    }
#define FMA4(rq, nq, ac)                                                       \
    ac[0] = fmaf(nq, bf2f(rq.x), ac[0]);                                       \
    ac[1] = fmaf(nq, bf2f(rq.y), ac[1]);                                       \
    ac[2] = fmaf(nq, bf2f(rq.z), ac[2]);                                       \
    ac[3] = fmaf(nq, bf2f(rq.w), ac[3]);

    {   // first 16 edges: unconditional, zero-dependency issue
        ushort4 r0, r1, r2, r3;
        float n0, n1, n2, n3;
        QUADX(0, 0, r0, n0)
        QUADX(1, 0, r1, n1)
        QUADX(2, 0, r2, n2)
        QUADX(3, 0, r3, n3)
        FMA4(r0, n0, acc0)
        FMA4(r1, n1, acc1)
        FMA4(r2, n2, acc2)
        FMA4(r3, n3, acc3)
    }
    if (deg > 16) {
        for (int j = 16; j < deg; j += 16) {
            ushort4 r0, r1, r2, r3;
            float n0, n1, n2, n3;
            QUADX(0, j, r0, n0)
            QUADX(1, j, r1, n1)
            QUADX(2, j, r2, n2)
            QUADX(3, j, r3, n3)
            FMA4(r0, n0, acc0)
            FMA4(r1, n1, acc1)
            FMA4(r2, n2, acc2)
            FMA4(r3, n3, acc3)
        }
    }
#undef QUADX
#undef FMA4

    float s0 = (acc0[0] + acc1[0]) + (acc2[0] + acc3[0]);
    float s1 = (acc0[1] + acc1[1]) + (acc2[1] + acc3[1]);
    float s2 = (acc0[2] + acc1[2]) + (acc2[2] + acc3[2]);
    float s3 = (acc0[3] + acc1[3]) + (acc2[3] + acc3[3]);

    s0 += __shfl_xor(s0, 16); s1 += __shfl_xor(s1, 16);
    s2 += __shfl_xor(s2, 16); s3 += __shfl_xor(s3, 16);
    s0 += __shfl_xor(s0, 32); s1 += __shfl_xor(s1, 32);
    s2 += __shfl_xor(s2, 32); s3 += __shfl_xor(s3, 32);

    if (g == 0) {
        const float dsq = di * di;
        float v0 = fmaxf(fmaf(dsq, bf2f(hs.x), bb.x) + s0, 0.f);
        float v1 = fmaxf(fmaf(dsq, bf2f(hs.y), bb.y) + s1, 0.f);
        float v2 = fmaxf(fmaf(dsq, bf2f(hs.z), bb.z) + s2, 0.f);
        float v3 = fmaxf(fmaf(dsq, bf2f(hs.w), bb.w) + s3, 0.f);
        float4 o;
        if (FINAL) {
            o.x = 0.5f * (p.x + v0); o.y = 0.5f * (p.y + v1);
            o.z = 0.5f * (p.z + v2); o.w = 0.5f * (p.w + v3);
        } else {
            o.x = v0; o.y = v1; o.z = v2; o.w = v3;
        }
        *(float4*)(out + (size_t)node * DD + l4) = o;
    }
}

__global__ __launch_bounds__(256) void gemm_mfma(
    const float* __restrict__ x, const float* __restrict__ W,
    unsigned short* __restrict__ h16)
{
    __shared__ unsigned short Xs[64 * 72];
    __shared__ unsigned short Ws[64 * 72];
    gemm_body(x, W, h16, blockIdx.x * 64, threadIdx.x, Xs, Ws);
}

// ============= launch =============

extern "C" void kernel_launch(void* const* d_in, const int* in_sizes, int n_in,
                              void* d_out, int out_size, void* d_ws, size_t ws_size,
                              hipStream_t stream) {
    const float* x   = (const float*)d_in[0];
    const int*   ei  = (const int*)d_in[1];
    const float* ewt = (const float*)d_in[2];
    const float* W1  = (const float*)d_in[3];
    const float* b1  = (const float*)d_in[4];
    const float* W2  = (const float*)d_in[5];
    const float* b2  = (const float*)d_in[6];
    float* out = (float*)d_out;

    const int* srcv = ei;
    const int* dstv = ei + NE;

    // workspace layout, 4B slots (d_ws 16B aligned); ~50 MB total
    float* wsf = (float*)d_ws;
    int* cursor = (int*)wsf;                                        // [0,256)
    unsigned int* degdis = (unsigned int*)(wsf + 4352);             // 100000 -> pad 104448
    unsigned long long* stage = (unsigned long long*)(wsf + 104448);// NBUCK*BCAP u64
    unsigned int* slots = (unsigned int*)(wsf + 104448 + 2 * NBUCK * BCAP);
    unsigned short* h16 = (unsigned short*)(slots + (size_t)NN * 64); // NN*64 bf16

    const int GB = (NN * 64) / 256;          // 25000 blocks, one wave per node

    hipMemsetAsync(cursor, 0, NBUCK * sizeof(int), stream);
    pass1_gemm<<<NB1 + NB_G, 256, 0, stream>>>(srcv, dstv, ewt, cursor, stage,
                                               x, W1, h16);
    pass2<<<NBUCK, 512, 0, stream>>>(stage, cursor, slots, degdis);

    gather<false><<<GB, 256, 0, stream>>>(h16, b1, degdis, slots, nullptr, out);
    gemm_mfma<<<NB_G, 256, 0, stream>>>(out, W2, h16);
    gather<true><<<GB, 256, 0, stream>>>(h16, b2, degdis, slots, out, out);
}

// Round 9
// 194.800 us; speedup vs baseline: 1.1058x; 1.0384x over previous
//
#include <hip/hip_runtime.h>

#define NN 100000
#define NE 1200000
#define DD 64
#define NBUCK 196        // ceil(NN/512) coarse buckets (dst >> 9)
#define BCAP 7168        // bucket capacity: mean 6144, sigma ~78 -> +13 sigma
#define TILE 4096        // edges per pass-1 block
#define NB1 293          // ceil(NE/TILE)
#define NB_G 1563        // ceil(NN/64) gemm blocks
#define FIX25 33554432.0f
#define FIX25_INV (1.0f/33554432.0f)

typedef short bf16x8 __attribute__((ext_vector_type(8)));
typedef float f32x4  __attribute__((ext_vector_type(4)));

static __device__ __forceinline__ unsigned short f2bf(float f) {
    unsigned int u = __float_as_uint(f);
    unsigned int r = (u + 0x7fffu + ((u >> 16) & 1u)) >> 16;   // RNE
    return (unsigned short)r;
}
static __device__ __forceinline__ float bf2f(unsigned short s) {
    return __uint_as_float(((unsigned int)s) << 16);
}

// ============= prep: zero cursors, W -> bf16^T =============
// Kept as a separate 3-block kernel: staging W^T from fp32 W inside each gemm
// block (r7/r8) costs 16 strided scalar loads/thread x 3126 block instances
// and measured +6 us vs this one-time coalesced transpose.

__global__ __launch_bounds__(256) void prep(
    int* __restrict__ cursor,
    const float* __restrict__ W1, const float* __restrict__ W2,
    unsigned short* __restrict__ Wt1, unsigned short* __restrict__ Wt2)
{
    if (blockIdx.x == 0) {
        if (threadIdx.x < NBUCK) cursor[threadIdx.x] = 0;
        return;
    }
    const float* W = (blockIdx.x == 1) ? W1 : W2;
    unsigned short* Wt = (blockIdx.x == 1) ? Wt1 : Wt2;
    int t = threadIdx.x;
    int col = t >> 2, k0 = (t & 3) * 16;
    #pragma unroll
    for (int i = 0; i < 16; ++i)
        Wt[col * 64 + k0 + i] = f2bf(W[(k0 + i) * 64 + col]);
}

// ============= shared GEMM body: h16 = bf16(x @ W) =============

static __device__ __forceinline__ void gemm_body(
    const float* __restrict__ x, const unsigned short* __restrict__ Wt,
    unsigned short* __restrict__ h16, int r0, int t,
    unsigned short* Xs, unsigned short* Ws)
{
    {   // stage Wt ([col][k] bf16): 16 ushorts/thread
        int col = t >> 2, seg = (t & 3) * 16;
        const uint4* p = (const uint4*)(Wt + col * 64 + seg);
        uint4 a0 = p[0], a1 = p[1];
        *(uint4*)&Ws[col * 72 + seg]     = a0;
        *(uint4*)&Ws[col * 72 + seg + 8] = a1;
    }
    {   // stage X: fp32 -> bf16, 16 floats/thread
        int row = t >> 2, seg = (t & 3) * 16;
        int gr = r0 + row;
        float4 v0 = {0,0,0,0}, v1 = v0, v2 = v0, v3 = v0;
        if (gr < NN) {
            const float4* p = (const float4*)(x + (size_t)gr * DD + seg);
            v0 = p[0]; v1 = p[1]; v2 = p[2]; v3 = p[3];
        }
        ushort4 h0 = { f2bf(v0.x), f2bf(v0.y), f2bf(v0.z), f2bf(v0.w) };
        ushort4 h1 = { f2bf(v1.x), f2bf(v1.y), f2bf(v1.z), f2bf(v1.w) };
        ushort4 h2 = { f2bf(v2.x), f2bf(v2.y), f2bf(v2.z), f2bf(v2.w) };
        ushort4 h3 = { f2bf(v3.x), f2bf(v3.y), f2bf(v3.z), f2bf(v3.w) };
        *(ushort4*)&Xs[row * 72 + seg]      = h0;
        *(ushort4*)&Xs[row * 72 + seg + 4]  = h1;
        *(ushort4*)&Xs[row * 72 + seg + 8]  = h2;
        *(ushort4*)&Xs[row * 72 + seg + 12] = h3;
    }
    __syncthreads();

    const int wv = t >> 6;
    const int ln = t & 63;
    const int m  = ln & 15;
    const int q  = ln >> 4;
    const int arow = wv * 16 + m;

    bf16x8 a0 = *(const bf16x8*)&Xs[arow * 72 + q * 8];
    bf16x8 a1 = *(const bf16x8*)&Xs[arow * 72 + 32 + q * 8];

    f32x4 acc[4];
    #pragma unroll
    for (int c = 0; c < 4; ++c) {
        bf16x8 b0 = *(const bf16x8*)&Ws[(c * 16 + m) * 72 + q * 8];
        bf16x8 b1 = *(const bf16x8*)&Ws[(c * 16 + m) * 72 + 32 + q * 8];
        f32x4 z = {0.f, 0.f, 0.f, 0.f};
        z = __builtin_amdgcn_mfma_f32_16x16x32_bf16(a0, b0, z, 0, 0, 0);
        z = __builtin_amdgcn_mfma_f32_16x16x32_bf16(a1, b1, z, 0, 0, 0);
        acc[c] = z;
    }

    #pragma unroll
    for (int r = 0; r < 4; ++r) {
        int grow = r0 + wv * 16 + q * 4 + r;
        if (grow < NN) {
            #pragma unroll
            for (int c = 0; c < 4; ++c)
                h16[(size_t)grow * DD + c * 16 + m] = f2bf(acc[c][r]);
        }
    }
}

// ============= pass 1: coarse binning (2-sweep, LDS counts) + gemm1 fused =====
// Blocks [0,NB1): bin TILE edges into NBUCK buckets; stage entry u64:
//   [dl:9 | src:17]:32 high, fp32 ew low. One cursor atomic per (block,bucket).
// Blocks [NB1, NB1+NB_G): layer-1 GEMM (independent -> co-scheduled).

__global__ __launch_bounds__(256) void pass1_gemm(
    const int* __restrict__ src, const int* __restrict__ dst,
    const float* __restrict__ ew, int* __restrict__ cursor,
    unsigned long long* __restrict__ stage,
    const float* __restrict__ x, const unsigned short* __restrict__ Wt1,
    unsigned short* __restrict__ h16)
{
    __shared__ unsigned short Xs[64 * 72];
    __shared__ unsigned short Ws[64 * 72];
    __shared__ int cnt[NBUCK];
    __shared__ int resv[NBUCK];

    const int t = threadIdx.x;

    if (blockIdx.x >= NB1) {
        gemm_body(x, Wt1, h16, (blockIdx.x - NB1) * 64, t, Xs, Ws);
        return;
    }

    const int base = blockIdx.x * TILE;
    if (t < NBUCK) cnt[t] = 0;
    __syncthreads();

    #pragma unroll
    for (int k = 0; k < TILE / 256; ++k) {
        int e = base + k * 256 + t;
        if (e < NE) atomicAdd(&cnt[dst[e] >> 9], 1);
    }
    __syncthreads();
    if (t < NBUCK) {
        int c = cnt[t];
        resv[t] = c ? atomicAdd(&cursor[t], c) : 0;
        cnt[t] = 0;
    }
    __syncthreads();
    #pragma unroll
    for (int k = 0; k < TILE / 256; ++k) {
        int e = base + k * 256 + t;
        if (e < NE) {
            int d = dst[e];
            int b = d >> 9;
            int r = atomicAdd(&cnt[b], 1);
            int pos = resv[b] + r;
            if (pos < BCAP) {
                unsigned int meta = ((unsigned int)(d & 511) << 17) |
                                    (unsigned int)src[e];
                stage[(size_t)b * BCAP + pos] =
                    ((unsigned long long)meta << 32) | __float_as_uint(ew[e]);
            }
        }
    }
}

// ============= pass 2: per-bucket rank -> fixed-stride slots + degdis ========
// One block (512 thr) per bucket, single sweep: LDS atomic rank r + fixpoint
// wsum; slot address is direct: slots[(n0+dl)*64 + r]. No staging, no scan.
// degdis[node] = (rsqrt(1+wsum) bits & ~63) | deg   (6 stolen mantissa bits
// cost ~2^-17 relative -- far below the bf16 norm quantization).
// No tail handling: stale words past deg decode to srow >= NN (harness
// poison) and gather clamps them to hot row 0 with norm masked 0. Measured:
// explicit tail-zeroing (r6) and bulk-zeroing (r7) are both net regressions.

__global__ __launch_bounds__(512) void pass2(
    const unsigned long long* __restrict__ stage, const int* __restrict__ cursor,
    unsigned int* __restrict__ slots, unsigned int* __restrict__ degdis)
{
    __shared__ int cnt[512];
    __shared__ unsigned sum[512];

    const int b = blockIdx.x;
    const int t = threadIdx.x;
    const int n0 = b << 9;
    const int cntb = min(cursor[b], BCAP);

    cnt[t] = 0; sum[t] = 0;
    __syncthreads();

    for (int k = t; k < cntb; k += 512) {
        unsigned long long E = stage[(size_t)b * BCAP + k];
        unsigned int meta = (unsigned int)(E >> 32);
        int dl = meta >> 17;
        float w = __uint_as_float((unsigned int)E);
        int r = atomicAdd(&cnt[dl], 1);
        atomicAdd(&sum[dl], (unsigned)(w * FIX25));
        if (r < 63)
            slots[(size_t)(n0 + dl) * 64 + r] =
                ((meta & 0x1ffffu) << 15) | (f2bf(w) & 0x7fffu);
    }
    __syncthreads();

    int node = n0 + t;
    if (node < NN) {
        float deg = 1.0f + (float)sum[t] * FIX25_INV;
        float di = rsqrtf(deg);
        degdis[node] = (__float_as_uint(di) & ~63u) |
                       (unsigned)min(cnt[t], 63);
    }
}

// ============= gather (one wave per node, 16-edge speculative issue) ========
// Lane = (g,l): g = lane>>4 edge slot in quad, l = lane&15 -> channels 4l..+3.
// Edge-word addresses depend only on `node`, so the first 16 words issue with
// NO prior load (2-level chain: word -> {h16 row, degdis[src]} in parallel).
// Norm computed in-flight from degdis (400 KB, L2-resident) -- no bake pass.
// 16-edge speculation is the measured knee: 32-wide is VALU-bound (r7,
// VALUBusy 94%, +15 us/gather). Stale tail words clamp to row 0, norm 0.

template <bool FINAL>
__global__ __launch_bounds__(256) void gather(
    const unsigned short* __restrict__ h16, const float* __restrict__ bias,
    const unsigned int* __restrict__ degdis, const unsigned int* __restrict__ slots,
    const float* __restrict__ prev, float* __restrict__ out)
{
    const int node = __builtin_amdgcn_readfirstlane(
        (blockIdx.x * blockDim.x + threadIdx.x) >> 6);
    const int lane = threadIdx.x & 63;
    if (node >= NN) return;

    const int g = lane >> 4;
    const int l = lane & 15;
    const int l4 = l << 2;

    const unsigned int* seg = slots + (size_t)node * 64;

    const unsigned int dd = degdis[node];
    const int deg = dd & 63;
    const float di = __uint_as_float(dd & ~63u);

    // parallel with edge chain; consumed only in the epilogue
    const ushort4 hs = *(const ushort4*)(h16 + (size_t)node * DD + l4);
    const float4  bb = *(const float4*)(bias + l4);
    float4 p = {0.f, 0.f, 0.f, 0.f};
    if (FINAL) p = *(const float4*)(prev + (size_t)node * DD + l4);

    f32x4 acc0 = {0,0,0,0}, acc1 = {0,0,0,0}, acc2 = {0,0,0,0}, acc3 = {0,0,0,0};

#define QUADX(q, joff, rq, nq)                                                 \
    {                                                                          \
        unsigned w0 = seg[(joff) + 4*q + 0], w1 = seg[(joff) + 4*q + 1];       \
        unsigned w2 = seg[(joff) + 4*q + 2], w3 = seg[(joff) + 4*q + 3];       \
        unsigned ea = (g & 1) ? w1 : w0;                                       \
        unsigned eb = (g & 1) ? w3 : w2;                                       \
        unsigned e  = (g & 2) ? eb : ea;                                       \
        unsigned srow = e >> 15;                                               \
        srow = (srow < NN) ? srow : 0u;                                        \
        float dsrc = __uint_as_float(degdis[srow] & ~63u);                     \
        rq = *(const ushort4*)(h16 + ((size_t)srow << 6) + l4);                \
        float nv_ = bf2f((unsigned short)(e & 0x7fffu)) * di * dsrc;           \
        nq = ((joff) + 4*q + g < deg) ? nv_ : 0.f;                             \
    }
#define FMA4(rq, nq, ac)                                                       \
    ac[0] = fmaf(nq, bf2f(rq.x), ac[0]);                                       \
    ac[1] = fmaf(nq, bf2f(rq.y), ac[1]);                                       \
    ac[2] = fmaf(nq, bf2f(rq.z), ac[2]);                                       \
    ac[3] = fmaf(nq, bf2f(rq.w), ac[3]);

    {   // first 16 edges: unconditional, zero-dependency issue
        ushort4 r0, r1, r2, r3;
        float n0, n1, n2, n3;
        QUADX(0, 0, r0, n0)
        QUADX(1, 0, r1, n1)
        QUADX(2, 0, r2, n2)
        QUADX(3, 0, r3, n3)
        FMA4(r0, n0, acc0)
        FMA4(r1, n1, acc1)
        FMA4(r2, n2, acc2)
        FMA4(r3, n3, acc3)
    }
    if (deg > 16) {
        for (int j = 16; j < deg; j += 16) {
            ushort4 r0, r1, r2, r3;
            float n0, n1, n2, n3;
            QUADX(0, j, r0, n0)
            QUADX(1, j, r1, n1)
            QUADX(2, j, r2, n2)
            QUADX(3, j, r3, n3)
            FMA4(r0, n0, acc0)
            FMA4(r1, n1, acc1)
            FMA4(r2, n2, acc2)
            FMA4(r3, n3, acc3)
        }
    }
#undef QUADX
#undef FMA4

    float s0 = (acc0[0] + acc1[0]) + (acc2[0] + acc3[0]);
    float s1 = (acc0[1] + acc1[1]) + (acc2[1] + acc3[1]);
    float s2 = (acc0[2] + acc1[2]) + (acc2[2] + acc3[2]);
    float s3 = (acc0[3] + acc1[3]) + (acc2[3] + acc3[3]);

    s0 += __shfl_xor(s0, 16); s1 += __shfl_xor(s1, 16);
    s2 += __shfl_xor(s2, 16); s3 += __shfl_xor(s3, 16);
    s0 += __shfl_xor(s0, 32); s1 += __shfl_xor(s1, 32);
    s2 += __shfl_xor(s2, 32); s3 += __shfl_xor(s3, 32);

    if (g == 0) {
        const float dsq = di * di;
        float v0 = fmaxf(fmaf(dsq, bf2f(hs.x), bb.x) + s0, 0.f);
        float v1 = fmaxf(fmaf(dsq, bf2f(hs.y), bb.y) + s1, 0.f);
        float v2 = fmaxf(fmaf(dsq, bf2f(hs.z), bb.z) + s2, 0.f);
        float v3 = fmaxf(fmaf(dsq, bf2f(hs.w), bb.w) + s3, 0.f);
        float4 o;
        if (FINAL) {
            o.x = 0.5f * (p.x + v0); o.y = 0.5f * (p.y + v1);
            o.z = 0.5f * (p.z + v2); o.w = 0.5f * (p.w + v3);
        } else {
            o.x = v0; o.y = v1; o.z = v2; o.w = v3;
        }
        *(float4*)(out + (size_t)node * DD + l4) = o;
    }
}

__global__ __launch_bounds__(256) void gemm_mfma(
    const float* __restrict__ x, const unsigned short* __restrict__ Wt,
    unsigned short* __restrict__ h16)
{
    __shared__ unsigned short Xs[64 * 72];
    __shared__ unsigned short Ws[64 * 72];
    gemm_body(x, Wt, h16, blockIdx.x * 64, threadIdx.x, Xs, Ws);
}

// ============= launch =============

extern "C" void kernel_launch(void* const* d_in, const int* in_sizes, int n_in,
                              void* d_out, int out_size, void* d_ws, size_t ws_size,
                              hipStream_t stream) {
    const float* x   = (const float*)d_in[0];
    const int*   ei  = (const int*)d_in[1];
    const float* ewt = (const float*)d_in[2];
    const float* W1  = (const float*)d_in[3];
    const float* b1  = (const float*)d_in[4];
    const float* W2  = (const float*)d_in[5];
    const float* b2  = (const float*)d_in[6];
    float* out = (float*)d_out;

    const int* srcv = ei;
    const int* dstv = ei + NE;

    // workspace layout, 4B slots (d_ws 16B aligned); ~50 MB total
    float* wsf = (float*)d_ws;
    int* cursor = (int*)wsf;                                        // [0,256)
    unsigned short* Wt1 = (unsigned short*)(wsf + 256);             // 4096 ushorts
    unsigned short* Wt2 = Wt1 + 4096;                               // 4096 ushorts
    unsigned int* degdis = (unsigned int*)(wsf + 4352);             // 100000 -> pad 104448
    unsigned long long* stage = (unsigned long long*)(wsf + 104448);// NBUCK*BCAP u64
    unsigned int* slots = (unsigned int*)(wsf + 104448 + 2 * NBUCK * BCAP);
    unsigned short* h16 = (unsigned short*)(slots + (size_t)NN * 64); // NN*64 bf16

    const int GB = (NN * 64) / 256;          // 25000 blocks, one wave per node

    prep<<<3, 256, 0, stream>>>(cursor, W1, W2, Wt1, Wt2);
    pass1_gemm<<<NB1 + NB_G, 256, 0, stream>>>(srcv, dstv, ewt, cursor, stage,
                                               x, Wt1, h16);
    pass2<<<NBUCK, 512, 0, stream>>>(stage, cursor, slots, degdis);

    gather<false><<<GB, 256, 0, stream>>>(h16, b1, degdis, slots, nullptr, out);
    gemm_mfma<<<NB_G, 256, 0, stream>>>(out, Wt2, h16);
    gather<true><<<GB, 256, 0, stream>>>(h16, b2, degdis, slots, out, out);
}